// Round 2
// baseline (1127.098 us; speedup 1.0000x reference)
//
#include <hip/hip_runtime.h>
#include <math.h>

#define SEQ 512
#define DMODEL 512
#define NHEAD 8
#define DHEAD 64

typedef float f32x4 __attribute__((ext_vector_type(4)));

// ---------------------------------------------------------------------------
// Kernel 1: q/k/v projections.  q = (query@Wq+bq)/8, k = key@Wk+bk, v = ...
// Plain 16x16 LDS-tiled GEMM, fp32, outputs into workspace laid out
// [l, h*64+d] (the pre-split-heads [L, DMODEL] matrix).
// ---------------------------------------------------------------------------
__global__ __launch_bounds__(256) void proj_kernel(
    const float* __restrict__ query, const float* __restrict__ key_in, const float* __restrict__ value,
    const float* __restrict__ Wq, const float* __restrict__ bq,
    const float* __restrict__ Wk, const float* __restrict__ bk,
    const float* __restrict__ Wv, const float* __restrict__ bv,
    float* __restrict__ ws)
{
    const int which = blockIdx.z;
    const float* A    = which == 0 ? query : (which == 1 ? key_in : value);
    const float* W    = which == 0 ? Wq    : (which == 1 ? Wk     : Wv);
    const float* bias = which == 0 ? bq    : (which == 1 ? bk     : bv);
    const float scale = which == 0 ? 0.125f : 1.0f;   // 1/sqrt(DHEAD)
    float* C = ws + (size_t)which * (SEQ * DMODEL);

    __shared__ float As[16][17];
    __shared__ float Bs[16][17];
    const int tx = threadIdx.x, ty = threadIdx.y;
    const int row = blockIdx.y * 16 + ty;
    const int col = blockIdx.x * 16 + tx;
    float acc = 0.f;
    for (int t = 0; t < DMODEL / 16; ++t) {
        As[ty][tx] = A[(size_t)row * DMODEL + t * 16 + tx];
        Bs[ty][tx] = W[(size_t)(t * 16 + ty) * DMODEL + col];
        __syncthreads();
        #pragma unroll
        for (int kk = 0; kk < 16; ++kk) acc += As[ty][kk] * Bs[kk][tx];
        __syncthreads();
    }
    C[(size_t)row * DMODEL + col] = scale * (acc + bias[col]);
}

// ---------------------------------------------------------------------------
// Kernel 2 (FUSED): logits + softmax + context for one (h,l).
//
// Phase 1 (logits): lane = 8*mi + di; lane owns 8 floats (2 float4) of the
//   d-axis for m-row (wave*8+mi); 16 iterations stream the full 512 m-rows.
//   3-step shfl_xor reduce over di (was 4-step over 16 lanes, 32 iters).
// Softmax: fp32 in LDS; probs stored back to LDS (phase 2 reads LDS, not HBM)
//   and written nontemporally to attn_out (it IS output 1, never re-read).
// Phase 2 (context): lane owns 8 floats of d for m-row (wave*8+mi); 16 iters;
//   NO per-iteration shuffles — one 3-step reduce over mi after the loop.
// rk/rv loads are nontemporal: the 1 GB single-use stream must not evict the
//   L2-resident ws_k/ws_v (1 MB each, reused by all 512 l-blocks per head).
// ---------------------------------------------------------------------------
__global__ __launch_bounds__(256) void attn_ctx_kernel(
    const float* __restrict__ rk, const float* __restrict__ rv,
    const float* __restrict__ ws_q, const float* __restrict__ ws_k,
    const float* __restrict__ ws_v, float* __restrict__ attn_out,
    float* __restrict__ ws_ctx)
{
    const int l = blockIdx.x, h = blockIdx.y;
    const int tid = threadIdx.x;
    const int wave = tid >> 6, lane = tid & 63;

    __shared__ float qrow[DHEAD];
    __shared__ float probs[SEQ];          // logits, then softmax probs
    __shared__ float part[4][DHEAD];
    __shared__ float sred[4];

    if (tid < DHEAD) qrow[tid] = ws_q[(size_t)l * DMODEL + h * DHEAD + tid];
    __syncthreads();

    // ---------------- phase 1: logits[m] = q . (k[m] + rk[l,m]) ------------
    {
        const int mi = lane >> 3;   // 0..7  (8 m-rows per wave per iter)
        const int di = lane & 7;    // 0..7  (8 floats of d per lane)
        float qv[8];
        #pragma unroll
        for (int j = 0; j < 8; ++j) qv[j] = qrow[8 * di + j];

        const float* rk_p = rk + ((size_t)h * SEQ + l) * SEQ * DHEAD
                               + (size_t)(wave * 8 + mi) * DHEAD + 8 * di;
        const float* k_p  = ws_k + (size_t)(wave * 8 + mi) * DMODEL + h * DHEAD + 8 * di;

        #pragma unroll 2
        for (int it = 0; it < 16; ++it) {
            f32x4 r0 = __builtin_nontemporal_load((const f32x4*)(rk_p));
            f32x4 r1 = __builtin_nontemporal_load((const f32x4*)(rk_p + 4));
            float4 k0 = *(const float4*)(k_p);
            float4 k1 = *(const float4*)(k_p + 4);
            float s = qv[0] * (k0.x + r0[0]) + qv[1] * (k0.y + r0[1])
                    + qv[2] * (k0.z + r0[2]) + qv[3] * (k0.w + r0[3])
                    + qv[4] * (k1.x + r1[0]) + qv[5] * (k1.y + r1[1])
                    + qv[6] * (k1.z + r1[2]) + qv[7] * (k1.w + r1[3]);
            s += __shfl_xor(s, 1, 64);
            s += __shfl_xor(s, 2, 64);
            s += __shfl_xor(s, 4, 64);
            if (di == 0) probs[it * 32 + wave * 8 + mi] = s;
            rk_p += 32 * DHEAD;
            k_p  += 32 * DMODEL;
        }
    }
    __syncthreads();

    // ---------------- softmax over 512 logits (each thread owns 2) ---------
    {
        const float l0 = probs[tid], l1 = probs[tid + 256];
        float v = fmaxf(l0, l1);
        #pragma unroll
        for (int off = 32; off >= 1; off >>= 1) v = fmaxf(v, __shfl_xor(v, off, 64));
        if (lane == 0) sred[wave] = v;
        __syncthreads();
        const float maxv = fmaxf(fmaxf(sred[0], sred[1]), fmaxf(sred[2], sred[3]));
        __syncthreads();
        const float e0 = expf(l0 - maxv), e1 = expf(l1 - maxv);
        v = e0 + e1;
        #pragma unroll
        for (int off = 32; off >= 1; off >>= 1) v += __shfl_xor(v, off, 64);
        if (lane == 0) sred[wave] = v;
        __syncthreads();
        const float inv = 1.0f / (sred[0] + sred[1] + sred[2] + sred[3]);
        const float p0 = e0 * inv, p1 = e1 * inv;
        probs[tid]       = p0;
        probs[tid + 256] = p1;
        const size_t abase = ((size_t)h * SEQ + l) * SEQ;
        __builtin_nontemporal_store(p0, &attn_out[abase + tid]);
        __builtin_nontemporal_store(p1, &attn_out[abase + tid + 256]);
    }
    __syncthreads();

    // ---------------- phase 2: ctx[d] = sum_m p[m] * (v[m] + rv[l,m]) ------
    {
        const int mi = lane >> 3;   // 0..7
        const int di = lane & 7;    // 0..7
        float acc[8];
        #pragma unroll
        for (int j = 0; j < 8; ++j) acc[j] = 0.f;

        const float* rv_p = rv + ((size_t)h * SEQ + l) * SEQ * DHEAD
                               + (size_t)(wave * 8 + mi) * DHEAD + 8 * di;
        const float* v_p  = ws_v + (size_t)(wave * 8 + mi) * DMODEL + h * DHEAD + 8 * di;
        int m = wave * 8 + mi;

        #pragma unroll 2
        for (int it = 0; it < 16; ++it) {
            const float a = probs[m];
            f32x4 r0 = __builtin_nontemporal_load((const f32x4*)(rv_p));
            f32x4 r1 = __builtin_nontemporal_load((const f32x4*)(rv_p + 4));
            float4 v0 = *(const float4*)(v_p);
            float4 v1 = *(const float4*)(v_p + 4);
            acc[0] += a * (v0.x + r0[0]);
            acc[1] += a * (v0.y + r0[1]);
            acc[2] += a * (v0.z + r0[2]);
            acc[3] += a * (v0.w + r0[3]);
            acc[4] += a * (v1.x + r1[0]);
            acc[5] += a * (v1.y + r1[1]);
            acc[6] += a * (v1.z + r1[2]);
            acc[7] += a * (v1.w + r1[3]);
            rv_p += 32 * DHEAD;
            v_p  += 32 * DMODEL;
            m += 32;
        }
        // reduce over mi (lane bits 3..5), once, after the stream
        #pragma unroll
        for (int j = 0; j < 8; ++j) {
            acc[j] += __shfl_xor(acc[j], 8, 64);
            acc[j] += __shfl_xor(acc[j], 16, 64);
            acc[j] += __shfl_xor(acc[j], 32, 64);
        }
        if (mi == 0) {
            #pragma unroll
            for (int j = 0; j < 8; ++j) part[wave][8 * di + j] = acc[j];
        }
    }
    __syncthreads();
    if (tid < DHEAD) {
        const float s = part[0][tid] + part[1][tid] + part[2][tid] + part[3][tid];
        ws_ctx[(size_t)l * DMODEL + h * DHEAD + tid] = s;
    }
}

// ---------------------------------------------------------------------------
// Kernel 3: output = context @ Wo + bo  (all fp32)
// ---------------------------------------------------------------------------
__global__ __launch_bounds__(256) void out_kernel(
    const float* __restrict__ ctx, const float* __restrict__ Wo,
    const float* __restrict__ bo, float* __restrict__ out)
{
    __shared__ float As[16][17];
    __shared__ float Bs[16][17];
    const int tx = threadIdx.x, ty = threadIdx.y;
    const int row = blockIdx.y * 16 + ty;
    const int col = blockIdx.x * 16 + tx;
    float acc = 0.f;
    for (int t = 0; t < DMODEL / 16; ++t) {
        As[ty][tx] = ctx[(size_t)row * DMODEL + t * 16 + tx];
        Bs[ty][tx] = Wo[(size_t)(t * 16 + ty) * DMODEL + col];
        __syncthreads();
        #pragma unroll
        for (int kk = 0; kk < 16; ++kk) acc += As[ty][kk] * Bs[kk][tx];
        __syncthreads();
    }
    out[(size_t)row * DMODEL + col] = acc + bo[col];
}

extern "C" void kernel_launch(void* const* d_in, const int* in_sizes, int n_in,
                              void* d_out, int out_size, void* d_ws, size_t ws_size,
                              hipStream_t stream)
{
    const float* query  = (const float*)d_in[0];
    const float* key_in = (const float*)d_in[1];
    const float* value  = (const float*)d_in[2];
    const float* rk     = (const float*)d_in[3];
    const float* rv     = (const float*)d_in[4];
    const float* Wq = (const float*)d_in[5];  const float* bq = (const float*)d_in[6];
    const float* Wk = (const float*)d_in[7];  const float* bk = (const float*)d_in[8];
    const float* Wv = (const float*)d_in[9];  const float* bv = (const float*)d_in[10];
    const float* Wo = (const float*)d_in[11]; const float* bo = (const float*)d_in[12];

    float* out      = (float*)d_out;                  // [512,512] output
    float* attn_out = out + (size_t)SEQ * DMODEL;     // [8,512,512] attn

    float* ws = (float*)d_ws;
    float* ws_q   = ws;                 // [512,512] fp32
    float* ws_k   = ws + 262144;        // [512,512] fp32
    float* ws_v   = ws + 524288;        // [512,512] fp32
    float* ws_ctx = ws + 786432;        // [512,512] fp32

    dim3 pb(16, 16);
    proj_kernel<<<dim3(32, 32, 3), pb, 0, stream>>>(query, key_in, value,
                                                    Wq, bq, Wk, bk, Wv, bv, ws);
    attn_ctx_kernel<<<dim3(512, 8), 256, 0, stream>>>(rk, rv, ws_q, ws_k, ws_v,
                                                      attn_out, ws_ctx);
    out_kernel<<<dim3(32, 32), pb, 0, stream>>>(ws_ctx, Wo, bo, out);
}